// Round 17
// baseline (707.468 us; speedup 1.0000x reference)
//
#include <hip/hip_runtime.h>

// GAT forward: bf16-MFMA projections (int8 k/v quant) fused with edge-count,
// CSR scan, scatter, block-CSR edge-parallel aggregate (LDS accumulation).
// N=50000, E=800000, IN_DIM=128, H=8, D=16.
// v stored LINEAR (fix of r16's head-mismatch: lane j's v dims 4j..4j+3 are
// in head j>>2, matching its quad-reduced score).

#define NEG_SLOPE 0.2f
#define CB 1024   // count-role blocks fused into proj kernel

typedef __attribute__((ext_vector_type(8))) short short8;   // 8 bf16
typedef __attribute__((ext_vector_type(4))) float f32x4;    // MFMA C/D frag

__device__ __forceinline__ unsigned short f2bf(float f) {
    unsigned int u = __builtin_bit_cast(unsigned int, f);
    u = (u + 0x7fffu + ((u >> 16) & 1u)) >> 16;   // RNE
    return (unsigned short)u;
}
__device__ __forceinline__ float bf2f(unsigned short s) {
    unsigned int u = (unsigned int)s << 16;
    return __builtin_bit_cast(float, u);
}

// ---------------------------------------------------------------------------
// Kernel 1: zero cnt + pack weights to MFMA-fragment-linear bf16.
// ---------------------------------------------------------------------------
__global__ __launch_bounds__(256) void zero_wconv_kernel(
    const float* __restrict__ Wq, const float* __restrict__ Wk,
    const float* __restrict__ Wv, const float* __restrict__ Wres,
    unsigned short* __restrict__ wpk, int* __restrict__ cnt, int n4)
{
    int t = blockIdx.x * 256 + threadIdx.x;
    if (t < 8192) {
        int l = t & 63;
        int v = t >> 6;
        int kk = v & 3;
        int wct = v >> 2;
        int ct = wct & 7;
        int w = wct >> 3;
        const float* W = (w == 0) ? Wq : (w == 1) ? Wk : (w == 2) ? Wv : Wres;
        const float* srcp = W + (size_t)(ct * 16 + (l & 15)) * 128 + kk * 32 + (l >> 4) * 8;
        float4 lo = *reinterpret_cast<const float4*>(srcp);
        float4 hi = *reinterpret_cast<const float4*>(srcp + 4);
        short8 o;
        o[0] = (short)f2bf(lo.x); o[1] = (short)f2bf(lo.y);
        o[2] = (short)f2bf(lo.z); o[3] = (short)f2bf(lo.w);
        o[4] = (short)f2bf(hi.x); o[5] = (short)f2bf(hi.y);
        o[6] = (short)f2bf(hi.z); o[7] = (short)f2bf(hi.w);
        *reinterpret_cast<short8*>(wpk + (size_t)t * 8) = o;
    } else {
        int u = t - 8192;
        if (u < n4) reinterpret_cast<int4*>(cnt)[u] = make_int4(0, 0, 0, 0);
    }
}

// ---------------------------------------------------------------------------
// Kernel 2: MFMA projections + fused edge-count.
// q,res -> bf16.  k,v -> int8 (two-pass quant), one 256B row per node:
//   bytes [0,128):   k linear — byte c     = k_i8[dim c]
//   bytes [128,256): v linear — byte 128+c = v_i8[dim c]
// scales bf16 pair: kvscl16[2n]=ksc, kvscl16[2n+1]=vsc.
// ---------------------------------------------------------------------------
__global__ __launch_bounds__(256) void proj_count_kernel(
    const float* __restrict__ h,
    const unsigned short* __restrict__ wpk,
    unsigned short* __restrict__ qb, unsigned char* __restrict__ kvb,
    unsigned short* __restrict__ kvscl16, unsigned short* __restrict__ resb,
    const int* __restrict__ dst, int* __restrict__ cnt,
    int N, int E, int PB)
{
    if (blockIdx.x >= PB) {
        int start = (blockIdx.x - PB) * 256 + threadIdx.x;
        for (int e = start; e < E; e += CB * 256)
            atomicAdd(&cnt[dst[e]], 1);
        return;
    }

    const int wid = threadIdx.x >> 6;
    const int lane = threadIdx.x & 63;
    const int row0 = blockIdx.x * 128 + wid * 32;
    const int r = lane & 15, g = lane >> 4;

    short8 afrag[2][4];
    #pragma unroll
    for (int grp = 0; grp < 2; ++grp) {
        int arow = row0 + grp * 16 + r;
        if (arow >= N) arow = N - 1;
        const float* hrow = h + (size_t)arow * 128 + g * 8;
        #pragma unroll
        for (int kk = 0; kk < 4; ++kk) {
            float4 lo = *reinterpret_cast<const float4*>(hrow + kk * 32);
            float4 hi = *reinterpret_cast<const float4*>(hrow + kk * 32 + 4);
            short8 a;
            a[0] = (short)f2bf(lo.x); a[1] = (short)f2bf(lo.y);
            a[2] = (short)f2bf(lo.z); a[3] = (short)f2bf(lo.w);
            a[4] = (short)f2bf(hi.x); a[5] = (short)f2bf(hi.y);
            a[6] = (short)f2bf(hi.z); a[7] = (short)f2bf(hi.w);
            afrag[grp][kk] = a;
        }
    }

    // ---- q (w=0) and res (w=3): per-ct accumulators, bf16 stores ----
    #pragma unroll
    for (int sec = 0; sec < 2; ++sec) {
        const int w = (sec == 0) ? 0 : 3;
        unsigned short* O = (sec == 0) ? qb : resb;
        #pragma unroll
        for (int ct = 0; ct < 8; ++ct) {
            const unsigned short* bp =
                wpk + ((size_t)((w * 8 + ct) * 4) * 64 + lane) * 8;
            f32x4 acc[2];
            acc[0] = (f32x4)(0.f); acc[1] = (f32x4)(0.f);
            #pragma unroll
            for (int kk = 0; kk < 4; ++kk) {
                short8 bfrag = *reinterpret_cast<const short8*>(bp + (size_t)kk * 512);
                acc[0] = __builtin_amdgcn_mfma_f32_16x16x32_bf16(
                    afrag[0][kk], bfrag, acc[0], 0, 0, 0);
                acc[1] = __builtin_amdgcn_mfma_f32_16x16x32_bf16(
                    afrag[1][kk], bfrag, acc[1], 0, 0, 0);
            }
            #pragma unroll
            for (int grp = 0; grp < 2; ++grp)
                #pragma unroll
                for (int j = 0; j < 4; ++j) {
                    int orow = row0 + grp * 16 + g * 4 + j;
                    if (orow < N)
                        O[(size_t)orow * 128 + ct * 16 + r] = f2bf(acc[grp][j]);
                }
        }
    }

    // ---- k (w=1) then v (w=2): two-pass int8 quantize, linear byte layout ----
    #pragma unroll
    for (int sec = 0; sec < 2; ++sec) {
        const int w = 1 + sec;

        float mx[2][4];
        #pragma unroll
        for (int grp = 0; grp < 2; ++grp)
            #pragma unroll
            for (int j = 0; j < 4; ++j) mx[grp][j] = 0.f;

        #pragma unroll
        for (int ct = 0; ct < 8; ++ct) {
            const unsigned short* bp =
                wpk + ((size_t)((w * 8 + ct) * 4) * 64 + lane) * 8;
            f32x4 acc[2];
            acc[0] = (f32x4)(0.f); acc[1] = (f32x4)(0.f);
            #pragma unroll
            for (int kk = 0; kk < 4; ++kk) {
                short8 bfrag = *reinterpret_cast<const short8*>(bp + (size_t)kk * 512);
                acc[0] = __builtin_amdgcn_mfma_f32_16x16x32_bf16(
                    afrag[0][kk], bfrag, acc[0], 0, 0, 0);
                acc[1] = __builtin_amdgcn_mfma_f32_16x16x32_bf16(
                    afrag[1][kk], bfrag, acc[1], 0, 0, 0);
            }
            #pragma unroll
            for (int grp = 0; grp < 2; ++grp)
                #pragma unroll
                for (int j = 0; j < 4; ++j)
                    mx[grp][j] = fmaxf(mx[grp][j], fabsf(acc[grp][j]));
        }

        float inv[2][4];
        #pragma unroll
        for (int grp = 0; grp < 2; ++grp)
            #pragma unroll
            for (int j = 0; j < 4; ++j) {
                float m = mx[grp][j];
                #pragma unroll
                for (int s = 1; s < 16; s <<= 1)
                    m = fmaxf(m, __shfl_xor(m, s, 64));
                inv[grp][j] = (m > 0.f) ? 127.f / m : 0.f;
                int orow = row0 + grp * 16 + g * 4 + j;
                if (orow < N && r == 0)
                    kvscl16[2 * orow + sec] = f2bf(m * (1.f / 127.f));
            }

        #pragma unroll
        for (int ct = 0; ct < 8; ++ct) {
            const unsigned short* bp =
                wpk + ((size_t)((w * 8 + ct) * 4) * 64 + lane) * 8;
            f32x4 acc[2];
            acc[0] = (f32x4)(0.f); acc[1] = (f32x4)(0.f);
            #pragma unroll
            for (int kk = 0; kk < 4; ++kk) {
                short8 bfrag = *reinterpret_cast<const short8*>(bp + (size_t)kk * 512);
                acc[0] = __builtin_amdgcn_mfma_f32_16x16x32_bf16(
                    afrag[0][kk], bfrag, acc[0], 0, 0, 0);
                acc[1] = __builtin_amdgcn_mfma_f32_16x16x32_bf16(
                    afrag[1][kk], bfrag, acc[1], 0, 0, 0);
            }
            #pragma unroll
            for (int grp = 0; grp < 2; ++grp)
                #pragma unroll
                for (int j = 0; j < 4; ++j) {
                    int orow = row0 + grp * 16 + g * 4 + j;
                    if (orow < N) {
                        int qv = (int)rintf(acc[grp][j] * inv[grp][j]);
                        int c = ct * 16 + r;
                        kvb[(size_t)orow * 256 + sec * 128 + c] =
                            (unsigned char)(signed char)qv;
                    }
                }
        }
    }
}

// ---------------------------------------------------------------------------
// CSR scan: blocksum -> scanfinal (inline 49-element bsum prefix).
// ---------------------------------------------------------------------------
__global__ __launch_bounds__(256) void blocksum_kernel(
    const int* __restrict__ cnt, int* __restrict__ bsum, int N)
{
    __shared__ int ws[4];
    const int tid = threadIdx.x;
    int base = blockIdx.x * 1024 + tid * 4;
    int s = 0;
    if (base + 3 < N) {
        int4 v = *reinterpret_cast<const int4*>(cnt + base);
        s = v.x + v.y + v.z + v.w;
    } else {
        for (int i = 0; i < 4; ++i)
            if (base + i < N) s += cnt[base + i];
    }
    #pragma unroll
    for (int m = 32; m >= 1; m >>= 1) s += __shfl_xor(s, m, 64);
    if ((tid & 63) == 0) ws[tid >> 6] = s;
    __syncthreads();
    if (tid == 0) bsum[blockIdx.x] = ws[0] + ws[1] + ws[2] + ws[3];
}

__global__ __launch_bounds__(256) void scanfinal_kernel(
    const int* __restrict__ cnt, const int* __restrict__ bsum,
    int* __restrict__ row_start, int* __restrict__ cursor,
    int N, int E, int NB)
{
    __shared__ int sboff;
    __shared__ int wsum[4];
    const int tid = threadIdx.x, lane = tid & 63, w = tid >> 6;

    if (tid < 64) {
        int v = (tid < NB && tid < blockIdx.x) ? bsum[tid] : 0;
        #pragma unroll
        for (int m = 32; m >= 1; m >>= 1) v += __shfl_xor(v, m, 64);
        if (tid == 0) sboff = v;
    }
    __syncthreads();

    int base = blockIdx.x * 1024 + tid * 4;
    int a0 = 0, a1 = 0, a2 = 0, a3 = 0;
    if (base + 3 < N) {
        int4 v = *reinterpret_cast<const int4*>(cnt + base);
        a0 = v.x; a1 = v.y; a2 = v.z; a3 = v.w;
    } else {
        if (base + 0 < N) a0 = cnt[base + 0];
        if (base + 1 < N) a1 = cnt[base + 1];
        if (base + 2 < N) a2 = cnt[base + 2];
        if (base + 3 < N) a3 = cnt[base + 3];
    }
    const int tsum = a0 + a1 + a2 + a3;
    int v = tsum;
    #pragma unroll
    for (int off = 1; off < 64; off <<= 1) {
        int t = __shfl_up(v, off, 64);
        if (lane >= off) v += t;
    }
    if (lane == 63) wsum[w] = v;
    __syncthreads();
    int woff = 0;
    for (int i = 0; i < w; ++i) woff += wsum[i];
    int run = sboff + woff + v - tsum;

    int r0 = run, r1 = run + a0, r2 = r1 + a1, r3 = r2 + a2;
    if (base + 3 < N) {
        int4 o = make_int4(r0, r1, r2, r3);
        *reinterpret_cast<int4*>(row_start + base) = o;
        *reinterpret_cast<int4*>(cursor + base) = o;
    } else {
        int rr[4] = {r0, r1, r2, r3};
        for (int i = 0; i < 4; ++i)
            if (base + i < N) { row_start[base + i] = rr[i]; cursor[base + i] = rr[i]; }
    }
    if (blockIdx.x == 0 && tid == 0) row_start[N] = E;
}

// ---------------------------------------------------------------------------
// Scatter: csr entry packs src (16 bits, N<65536) + dst&15 (4 bits).
// ---------------------------------------------------------------------------
__global__ __launch_bounds__(256) void scatter_kernel(
    const int* __restrict__ src, const int* __restrict__ dst,
    int* __restrict__ cursor, unsigned int* __restrict__ csr, int E)
{
    int e = blockIdx.x * 256 + threadIdx.x;
    if (e < E) {
        int d = dst[e];
        int pos = atomicAdd(&cursor[d], 1);
        csr[pos] = (unsigned int)src[e] | ((unsigned int)(d & 15) << 16);
    }
}

// ---------------------------------------------------------------------------
// Block-CSR edge-parallel aggregate. Block owns 16 dst nodes (N = 3125*16).
// q rows staged in LDS (f32); edges processed edge-parallel (4 waves x 2
// halves, 32 lanes/edge); z and ex*v accumulated via LDS atomics; final
// normalize + residual + coalesced write.
// Lane j: k dims 4j..4j+3 (dot), v dims 4j..4j+3 (accumulate) — both in
// head j>>2, matching the quad-reduced score.
// ---------------------------------------------------------------------------
__global__ __launch_bounds__(256) void block_agg_kernel(
    const unsigned short* __restrict__ qb,
    const unsigned char* __restrict__ kvb,
    const unsigned int* __restrict__ kvscl32,
    const unsigned short* __restrict__ resb,
    const int* __restrict__ row_start, const unsigned int* __restrict__ csr,
    float* __restrict__ rst, int N)
{
    __shared__ float qs[16][128];
    __shared__ float rs[16][128];
    __shared__ float zs[16][8];

    const int tid = threadIdx.x;
    const int n0 = blockIdx.x * 16;

    // stage q (16x128 bf16 -> f32), zero rs and zs
    {
        const unsigned short* qsrc = qb + (size_t)n0 * 128 + tid * 8;
        ushort4 lo = *reinterpret_cast<const ushort4*>(qsrc);
        ushort4 hi = *reinterpret_cast<const ushort4*>(qsrc + 4);
        const int row = tid >> 4, col = (tid & 15) * 8;
        qs[row][col + 0] = bf2f(lo.x); qs[row][col + 1] = bf2f(lo.y);
        qs[row][col + 2] = bf2f(lo.z); qs[row][col + 3] = bf2f(lo.w);
        qs[row][col + 4] = bf2f(hi.x); qs[row][col + 5] = bf2f(hi.y);
        qs[row][col + 6] = bf2f(hi.z); qs[row][col + 7] = bf2f(hi.w);
        float* rz = &rs[0][0];
        #pragma unroll
        for (int i = 0; i < 8; ++i) rz[tid * 8 + i] = 0.f;
        if (tid < 128) (&zs[0][0])[tid] = 0.f;
    }
    __syncthreads();

    const int e0 = row_start[n0];
    const int e1 = row_start[n0 + 16];
    const int lane = tid & 63;
    const int j = lane & 31;
    const int half = lane >> 5;
    const int wid = tid >> 6;
    const int hq = j >> 2;

    for (int s = e0 + wid * 2 + half; s < e1; s += 8) {
        const unsigned int pk = csr[s];
        const int srcn = pk & 0xffff;
        const int dl = (pk >> 16) & 15;
        const unsigned int sw = kvscl32[srcn];
        const unsigned char* rowp = kvb + (size_t)srcn * 256;
        const unsigned int kdw = *reinterpret_cast<const unsigned int*>(rowp + 4 * j);
        const unsigned int vdw = *reinterpret_cast<const unsigned int*>(rowp + 128 + 4 * j);

        float4 q4 = *reinterpret_cast<const float4*>(&qs[dl][4 * j]);
        float p = q4.x * (float)(signed char)(kdw)
                + q4.y * (float)(signed char)(kdw >> 8)
                + q4.z * (float)(signed char)(kdw >> 16)
                + q4.w * (float)(signed char)(kdw >> 24);
        p += __shfl_xor(p, 1, 64);
        p += __shfl_xor(p, 2, 64);
        p *= bf2f((unsigned short)(sw & 0xffff));
        float e = (p >= 0.f) ? p : NEG_SLOPE * p;
        e = __expf(e);
        if ((j & 3) == 0) atomicAdd(&zs[dl][hq], e);
        const float f = e * bf2f((unsigned short)(sw >> 16));
        // v linear: lane j's dword = dims 4j..4j+3 (head j>>2 = e's head)
        atomicAdd(&rs[dl][4 * j + 0], f * (float)(signed char)(vdw));
        atomicAdd(&rs[dl][4 * j + 1], f * (float)(signed char)(vdw >> 8));
        atomicAdd(&rs[dl][4 * j + 2], f * (float)(signed char)(vdw >> 16));
        atomicAdd(&rs[dl][4 * j + 3], f * (float)(signed char)(vdw >> 24));
    }
    __syncthreads();

    // normalize + residual + write (thread t: node t>>4, dims (t&15)*8..+8)
    {
        const int dl = tid >> 4;
        const int d0 = (tid & 15) * 8;
        const int n = n0 + dl;
        const unsigned short* rrow = resb + (size_t)n * 128 + d0;
        float* orow = rst + (size_t)n * 128 + d0;
        #pragma unroll
        for (int i = 0; i < 8; ++i) {
            const int d = d0 + i;
            const float z = zs[dl][d >> 4];
            const float inv = (z > 0.f) ? 1.f / z : 0.f;
            orow[i] = bf2f(rrow[i]) + rs[dl][d] * inv;
        }
    }
}

extern "C" void kernel_launch(void* const* d_in, const int* in_sizes, int n_in,
                              void* d_out, int out_size, void* d_ws, size_t ws_size,
                              hipStream_t stream) {
    const float* h    = (const float*)d_in[0];
    const int*   src  = (const int*)d_in[2];
    const int*   dst  = (const int*)d_in[3];
    const float* Wq   = (const float*)d_in[4];
    const float* Wk   = (const float*)d_in[5];
    const float* Wv   = (const float*)d_in[6];
    const float* Wres = (const float*)d_in[8];
    float* rst = (float*)d_out;

    const int N = in_sizes[0] / 128;   // 50000
    const int E = in_sizes[2];         // 800000

    unsigned short* qb    = (unsigned short*)d_ws;          // N*128 bf16
    unsigned short* resb  = qb + (size_t)N * 128;           // N*128 bf16
    unsigned char*  kvb   = (unsigned char*)(resb + (size_t)N * 128); // N*256 u8
    unsigned short* kvscl = (unsigned short*)(kvb + (size_t)N * 256); // 2N bf16
    unsigned short* wpk   = kvscl + 2 * N;                  // 65536 bf16
    int* cnt       = (int*)(wpk + 4 * 16384);
    int* row_start = cnt + N;          // N+1
    int* cursor    = row_start + (N + 1);
    int* csr       = cursor + N;       // E entries (packed src|dloc)
    int* bsum      = csr + E + 64;

    const int n4 = N / 4;              // 12500
    const int NB = (N + 1023) / 1024;  // 49 <= 64
    const int PB = (N + 127) / 128;    // proj blocks

    zero_wconv_kernel<<<(8192 + n4 + 255) / 256, 256, 0, stream>>>(
        Wq, Wk, Wv, Wres, wpk, cnt, n4);
    proj_count_kernel<<<PB + CB, 256, 0, stream>>>(
        h, wpk, qb, kvb, kvscl, resb, dst, cnt, N, E, PB);
    blocksum_kernel<<<NB, 256, 0, stream>>>(cnt, bsum, N);
    scanfinal_kernel<<<NB, 256, 0, stream>>>(cnt, bsum, row_start, cursor,
                                             N, E, NB);
    scatter_kernel<<<(E + 255) / 256, 256, 0, stream>>>(src, dst, cursor,
                                                        (unsigned int*)csr, E);
    block_agg_kernel<<<N / 16, 256, 0, stream>>>(
        qb, kvb, (const unsigned int*)kvscl, resb, row_start,
        (const unsigned int*)csr, rst, N);
}

// Round 18
// 161.704 us; speedup vs baseline: 4.3751x; 4.3751x over previous
//
#include <hip/hip_runtime.h>

// GAT forward: bf16-MFMA projections (int8 k/v quant) fused with edge-count,
// CSR scan, scatter, head-per-lane fused aggregate (no cross-lane ops in the
// edge loop; 8 edges in flight per wave).
// N=50000, E=800000, IN_DIM=128, H=8, D=16.

#define NEG_SLOPE 0.2f
#define CB 1024   // count-role blocks fused into proj kernel

typedef __attribute__((ext_vector_type(8))) short short8;   // 8 bf16
typedef __attribute__((ext_vector_type(4))) float f32x4;    // MFMA C/D frag

__device__ __forceinline__ unsigned short f2bf(float f) {
    unsigned int u = __builtin_bit_cast(unsigned int, f);
    u = (u + 0x7fffu + ((u >> 16) & 1u)) >> 16;   // RNE
    return (unsigned short)u;
}
__device__ __forceinline__ float bf2f(unsigned short s) {
    unsigned int u = (unsigned int)s << 16;
    return __builtin_bit_cast(float, u);
}

// ---------------------------------------------------------------------------
// Kernel 1: zero cnt + zero csr prefetch pad + pack weights to
// MFMA-fragment-linear bf16.
// ---------------------------------------------------------------------------
__global__ __launch_bounds__(256) void zero_wconv_kernel(
    const float* __restrict__ Wq, const float* __restrict__ Wk,
    const float* __restrict__ Wv, const float* __restrict__ Wres,
    unsigned short* __restrict__ wpk, int* __restrict__ cnt,
    int* __restrict__ csr_pad, int n4)
{
    int t = blockIdx.x * 256 + threadIdx.x;
    if (t < 8192) {
        int l = t & 63;
        int v = t >> 6;
        int kk = v & 3;
        int wct = v >> 2;
        int ct = wct & 7;
        int w = wct >> 3;
        const float* W = (w == 0) ? Wq : (w == 1) ? Wk : (w == 2) ? Wv : Wres;
        const float* srcp = W + (size_t)(ct * 16 + (l & 15)) * 128 + kk * 32 + (l >> 4) * 8;
        float4 lo = *reinterpret_cast<const float4*>(srcp);
        float4 hi = *reinterpret_cast<const float4*>(srcp + 4);
        short8 o;
        o[0] = (short)f2bf(lo.x); o[1] = (short)f2bf(lo.y);
        o[2] = (short)f2bf(lo.z); o[3] = (short)f2bf(lo.w);
        o[4] = (short)f2bf(hi.x); o[5] = (short)f2bf(hi.y);
        o[6] = (short)f2bf(hi.z); o[7] = (short)f2bf(hi.w);
        *reinterpret_cast<short8*>(wpk + (size_t)t * 8) = o;
        if (t < 64) csr_pad[t] = 0;   // zero the pad past csr_src[E]
    } else {
        int u = t - 8192;
        if (u < n4) reinterpret_cast<int4*>(cnt)[u] = make_int4(0, 0, 0, 0);
    }
}

// ---------------------------------------------------------------------------
// Kernel 2: MFMA projections + fused edge-count.
// q,res -> bf16.  k,v -> int8 (two-pass quant), one 256B row per node:
//   bytes [0,128):   k linear — byte c     = k_i8[dim c]
//   bytes [128,256): v linear — byte 128+c = v_i8[dim c]
// scales bf16 pair: kvscl16[2n]=ksc, kvscl16[2n+1]=vsc.
// ---------------------------------------------------------------------------
__global__ __launch_bounds__(256) void proj_count_kernel(
    const float* __restrict__ h,
    const unsigned short* __restrict__ wpk,
    unsigned short* __restrict__ qb, unsigned char* __restrict__ kvb,
    unsigned short* __restrict__ kvscl16, unsigned short* __restrict__ resb,
    const int* __restrict__ dst, int* __restrict__ cnt,
    int N, int E, int PB)
{
    if (blockIdx.x >= PB) {
        int start = (blockIdx.x - PB) * 256 + threadIdx.x;
        for (int e = start; e < E; e += CB * 256)
            atomicAdd(&cnt[dst[e]], 1);
        return;
    }

    const int wid = threadIdx.x >> 6;
    const int lane = threadIdx.x & 63;
    const int row0 = blockIdx.x * 128 + wid * 32;
    const int r = lane & 15, g = lane >> 4;

    short8 afrag[2][4];
    #pragma unroll
    for (int grp = 0; grp < 2; ++grp) {
        int arow = row0 + grp * 16 + r;
        if (arow >= N) arow = N - 1;
        const float* hrow = h + (size_t)arow * 128 + g * 8;
        #pragma unroll
        for (int kk = 0; kk < 4; ++kk) {
            float4 lo = *reinterpret_cast<const float4*>(hrow + kk * 32);
            float4 hi = *reinterpret_cast<const float4*>(hrow + kk * 32 + 4);
            short8 a;
            a[0] = (short)f2bf(lo.x); a[1] = (short)f2bf(lo.y);
            a[2] = (short)f2bf(lo.z); a[3] = (short)f2bf(lo.w);
            a[4] = (short)f2bf(hi.x); a[5] = (short)f2bf(hi.y);
            a[6] = (short)f2bf(hi.z); a[7] = (short)f2bf(hi.w);
            afrag[grp][kk] = a;
        }
    }

    // ---- q (w=0) and res (w=3): per-ct accumulators, bf16 stores ----
    #pragma unroll
    for (int sec = 0; sec < 2; ++sec) {
        const int w = (sec == 0) ? 0 : 3;
        unsigned short* O = (sec == 0) ? qb : resb;
        #pragma unroll
        for (int ct = 0; ct < 8; ++ct) {
            const unsigned short* bp =
                wpk + ((size_t)((w * 8 + ct) * 4) * 64 + lane) * 8;
            f32x4 acc[2];
            acc[0] = (f32x4)(0.f); acc[1] = (f32x4)(0.f);
            #pragma unroll
            for (int kk = 0; kk < 4; ++kk) {
                short8 bfrag = *reinterpret_cast<const short8*>(bp + (size_t)kk * 512);
                acc[0] = __builtin_amdgcn_mfma_f32_16x16x32_bf16(
                    afrag[0][kk], bfrag, acc[0], 0, 0, 0);
                acc[1] = __builtin_amdgcn_mfma_f32_16x16x32_bf16(
                    afrag[1][kk], bfrag, acc[1], 0, 0, 0);
            }
            #pragma unroll
            for (int grp = 0; grp < 2; ++grp)
                #pragma unroll
                for (int j = 0; j < 4; ++j) {
                    int orow = row0 + grp * 16 + g * 4 + j;
                    if (orow < N)
                        O[(size_t)orow * 128 + ct * 16 + r] = f2bf(acc[grp][j]);
                }
        }
    }

    // ---- k (w=1) then v (w=2): two-pass int8 quantize, linear layout ----
    #pragma unroll
    for (int sec = 0; sec < 2; ++sec) {
        const int w = 1 + sec;

        float mx[2][4];
        #pragma unroll
        for (int grp = 0; grp < 2; ++grp)
            #pragma unroll
            for (int j = 0; j < 4; ++j) mx[grp][j] = 0.f;

        #pragma unroll
        for (int ct = 0; ct < 8; ++ct) {
            const unsigned short* bp =
                wpk + ((size_t)((w * 8 + ct) * 4) * 64 + lane) * 8;
            f32x4 acc[2];
            acc[0] = (f32x4)(0.f); acc[1] = (f32x4)(0.f);
            #pragma unroll
            for (int kk = 0; kk < 4; ++kk) {
                short8 bfrag = *reinterpret_cast<const short8*>(bp + (size_t)kk * 512);
                acc[0] = __builtin_amdgcn_mfma_f32_16x16x32_bf16(
                    afrag[0][kk], bfrag, acc[0], 0, 0, 0);
                acc[1] = __builtin_amdgcn_mfma_f32_16x16x32_bf16(
                    afrag[1][kk], bfrag, acc[1], 0, 0, 0);
            }
            #pragma unroll
            for (int grp = 0; grp < 2; ++grp)
                #pragma unroll
                for (int j = 0; j < 4; ++j)
                    mx[grp][j] = fmaxf(mx[grp][j], fabsf(acc[grp][j]));
        }

        float inv[2][4];
        #pragma unroll
        for (int grp = 0; grp < 2; ++grp)
            #pragma unroll
            for (int j = 0; j < 4; ++j) {
                float m = mx[grp][j];
                #pragma unroll
                for (int s = 1; s < 16; s <<= 1)
                    m = fmaxf(m, __shfl_xor(m, s, 64));
                inv[grp][j] = (m > 0.f) ? 127.f / m : 0.f;
                int orow = row0 + grp * 16 + g * 4 + j;
                if (orow < N && r == 0)
                    kvscl16[2 * orow + sec] = f2bf(m * (1.f / 127.f));
            }

        #pragma unroll
        for (int ct = 0; ct < 8; ++ct) {
            const unsigned short* bp =
                wpk + ((size_t)((w * 8 + ct) * 4) * 64 + lane) * 8;
            f32x4 acc[2];
            acc[0] = (f32x4)(0.f); acc[1] = (f32x4)(0.f);
            #pragma unroll
            for (int kk = 0; kk < 4; ++kk) {
                short8 bfrag = *reinterpret_cast<const short8*>(bp + (size_t)kk * 512);
                acc[0] = __builtin_amdgcn_mfma_f32_16x16x32_bf16(
                    afrag[0][kk], bfrag, acc[0], 0, 0, 0);
                acc[1] = __builtin_amdgcn_mfma_f32_16x16x32_bf16(
                    afrag[1][kk], bfrag, acc[1], 0, 0, 0);
            }
            #pragma unroll
            for (int grp = 0; grp < 2; ++grp)
                #pragma unroll
                for (int j = 0; j < 4; ++j) {
                    int orow = row0 + grp * 16 + g * 4 + j;
                    if (orow < N) {
                        int qv = (int)rintf(acc[grp][j] * inv[grp][j]);
                        int c = ct * 16 + r;
                        kvb[(size_t)orow * 256 + sec * 128 + c] =
                            (unsigned char)(signed char)qv;
                    }
                }
        }
    }
}

// ---------------------------------------------------------------------------
// CSR scan: blocksum -> scanfinal (inline 49-element bsum prefix).
// ---------------------------------------------------------------------------
__global__ __launch_bounds__(256) void blocksum_kernel(
    const int* __restrict__ cnt, int* __restrict__ bsum, int N)
{
    __shared__ int ws[4];
    const int tid = threadIdx.x;
    int base = blockIdx.x * 1024 + tid * 4;
    int s = 0;
    if (base + 3 < N) {
        int4 v = *reinterpret_cast<const int4*>(cnt + base);
        s = v.x + v.y + v.z + v.w;
    } else {
        for (int i = 0; i < 4; ++i)
            if (base + i < N) s += cnt[base + i];
    }
    #pragma unroll
    for (int m = 32; m >= 1; m >>= 1) s += __shfl_xor(s, m, 64);
    if ((tid & 63) == 0) ws[tid >> 6] = s;
    __syncthreads();
    if (tid == 0) bsum[blockIdx.x] = ws[0] + ws[1] + ws[2] + ws[3];
}

__global__ __launch_bounds__(256) void scanfinal_kernel(
    const int* __restrict__ cnt, const int* __restrict__ bsum,
    int* __restrict__ row_start, int* __restrict__ cursor,
    int N, int E, int NB)
{
    __shared__ int sboff;
    __shared__ int wsum[4];
    const int tid = threadIdx.x, lane = tid & 63, w = tid >> 6;

    if (tid < 64) {
        int v = (tid < NB && tid < blockIdx.x) ? bsum[tid] : 0;
        #pragma unroll
        for (int m = 32; m >= 1; m >>= 1) v += __shfl_xor(v, m, 64);
        if (tid == 0) sboff = v;
    }
    __syncthreads();

    int base = blockIdx.x * 1024 + tid * 4;
    int a0 = 0, a1 = 0, a2 = 0, a3 = 0;
    if (base + 3 < N) {
        int4 v = *reinterpret_cast<const int4*>(cnt + base);
        a0 = v.x; a1 = v.y; a2 = v.z; a3 = v.w;
    } else {
        if (base + 0 < N) a0 = cnt[base + 0];
        if (base + 1 < N) a1 = cnt[base + 1];
        if (base + 2 < N) a2 = cnt[base + 2];
        if (base + 3 < N) a3 = cnt[base + 3];
    }
    const int tsum = a0 + a1 + a2 + a3;
    int v = tsum;
    #pragma unroll
    for (int off = 1; off < 64; off <<= 1) {
        int t = __shfl_up(v, off, 64);
        if (lane >= off) v += t;
    }
    if (lane == 63) wsum[w] = v;
    __syncthreads();
    int woff = 0;
    for (int i = 0; i < w; ++i) woff += wsum[i];
    int run = sboff + woff + v - tsum;

    int r0 = run, r1 = run + a0, r2 = r1 + a1, r3 = r2 + a2;
    if (base + 3 < N) {
        int4 o = make_int4(r0, r1, r2, r3);
        *reinterpret_cast<int4*>(row_start + base) = o;
        *reinterpret_cast<int4*>(cursor + base) = o;
    } else {
        int rr[4] = {r0, r1, r2, r3};
        for (int i = 0; i < 4; ++i)
            if (base + i < N) { row_start[base + i] = rr[i]; cursor[base + i] = rr[i]; }
    }
    if (blockIdx.x == 0 && tid == 0) row_start[N] = E;
}

__global__ __launch_bounds__(256) void scatter_kernel(
    const int* __restrict__ src, const int* __restrict__ dst,
    int* __restrict__ cursor, int* __restrict__ csr_src, int E)
{
    int e = blockIdx.x * 256 + threadIdx.x;
    if (e < E) {
        int d = dst[e];
        int pos = atomicAdd(&cursor[d], 1);
        csr_src[pos] = src[e];
    }
}

// ---------------------------------------------------------------------------
// Head-per-lane fused aggregate. One wave per node; 8 edge-slots (g) x
// 8 head-lanes (i). Lane (g,i): head i of edge base+g — k dot (16 local
// FMAs), e/z/alpha lane-local, v accumulate into acc[16] registers.
// NO cross-lane ops in the loop; one 3-step shfl_xor combine at the end.
// ---------------------------------------------------------------------------
__global__ __launch_bounds__(256) void head_agg_kernel(
    const unsigned short* __restrict__ qb,
    const unsigned char* __restrict__ kvb,
    const unsigned int* __restrict__ kvscl32,
    const unsigned short* __restrict__ resb,
    const int* __restrict__ row_start, const int* __restrict__ csr_src,
    float* __restrict__ rst, int N)
{
    const int lane = threadIdx.x & 63;
    const int g = lane >> 3;      // edge slot 0..7
    const int i = lane & 7;       // head index 0..7
    const int node = blockIdx.x * 4 + (threadIdx.x >> 6);
    if (node >= N) return;

    const int beg = row_start[node];
    const int end = row_start[node + 1];
    const int nE = end - beg;

    // preload q dims 16i..16i+15 (head i) as f32
    float q[16];
    {
        const unsigned short* qp = qb + (size_t)node * 128 + 16 * i;
        #pragma unroll
        for (int t = 0; t < 4; ++t) {
            ushort4 u = *reinterpret_cast<const ushort4*>(qp + 4 * t);
            q[4 * t + 0] = bf2f(u.x); q[4 * t + 1] = bf2f(u.y);
            q[4 * t + 2] = bf2f(u.z); q[4 * t + 3] = bf2f(u.w);
        }
    }

    float acc[16];
    #pragma unroll
    for (int t = 0; t < 16; ++t) acc[t] = 0.f;
    float z = 0.f;

    for (int base = beg; base < end; base += 8) {
        const int idx = base + g;
        const float m = (idx < end) ? 1.f : 0.f;
        const int srcn = csr_src[idx];       // 64-entry zero pad -> safe
        const unsigned int sw = kvscl32[srcn];
        const unsigned char* rowp = kvb + (size_t)srcn * 256;
        int4 kq = *reinterpret_cast<const int4*>(rowp + 16 * i);
        int4 vq = *reinterpret_cast<const int4*>(rowp + 128 + 16 * i);

        const unsigned int kw0 = (unsigned int)kq.x, kw1 = (unsigned int)kq.y,
                           kw2 = (unsigned int)kq.z, kw3 = (unsigned int)kq.w;
        float p = 0.f;
        p = fmaf(q[0],  (float)(signed char)(kw0),        p);
        p = fmaf(q[1],  (float)(signed char)(kw0 >> 8),   p);
        p = fmaf(q[2],  (float)(signed char)(kw0 >> 16),  p);
        p = fmaf(q[3],  (float)(signed char)(kw0 >> 24),  p);
        p = fmaf(q[4],  (float)(signed char)(kw1),        p);
        p = fmaf(q[5],  (float)(signed char)(kw1 >> 8),   p);
        p = fmaf(q[6],  (float)(signed char)(kw1 >> 16),  p);
        p = fmaf(q[7],  (float)(signed char)(kw1 >> 24),  p);
        p = fmaf(q[8],  (float)(signed char)(kw2),        p);
        p = fmaf(q[9],  (float)(signed char)(kw2 >> 8),   p);
        p = fmaf(q[10], (float)(signed char)(kw2 >> 16),  p);
        p = fmaf(q[11], (float)(signed char)(kw2 >> 24),  p);
        p = fmaf(q[12], (float)(signed char)(kw3),        p);
        p = fmaf(q[13], (float)(signed char)(kw3 >> 8),   p);
        p = fmaf(q[14], (float)(signed char)(kw3 >> 16),  p);
        p = fmaf(q[15], (float)(signed char)(kw3 >> 24),  p);

        p *= bf2f((unsigned short)(sw & 0xffff));
        float e = (p >= 0.f) ? p : NEG_SLOPE * p;
        e = m * __expf(e);
        z += e;
        const float f = e * bf2f((unsigned short)(sw >> 16));

        const unsigned int vw0 = (unsigned int)vq.x, vw1 = (unsigned int)vq.y,
                           vw2 = (unsigned int)vq.z, vw3 = (unsigned int)vq.w;
        acc[0]  = fmaf(f, (float)(signed char)(vw0),       acc[0]);
        acc[1]  = fmaf(f, (float)(signed char)(vw0 >> 8),  acc[1]);
        acc[2]  = fmaf(f, (float)(signed char)(vw0 >> 16), acc[2]);
        acc[3]  = fmaf(f, (float)(signed char)(vw0 >> 24), acc[3]);
        acc[4]  = fmaf(f, (float)(signed char)(vw1),       acc[4]);
        acc[5]  = fmaf(f, (float)(signed char)(vw1 >> 8),  acc[5]);
        acc[6]  = fmaf(f, (float)(signed char)(vw1 >> 16), acc[6]);
        acc[7]  = fmaf(f, (float)(signed char)(vw1 >> 24), acc[7]);
        acc[8]  = fmaf(f, (float)(signed char)(vw2),       acc[8]);
        acc[9]  = fmaf(f, (float)(signed char)(vw2 >> 8),  acc[9]);
        acc[10] = fmaf(f, (float)(signed char)(vw2 >> 16), acc[10]);
        acc[11] = fmaf(f, (float)(signed char)(vw2 >> 24), acc[11]);
        acc[12] = fmaf(f, (float)(signed char)(vw3),       acc[12]);
        acc[13] = fmaf(f, (float)(signed char)(vw3 >> 8),  acc[13]);
        acc[14] = fmaf(f, (float)(signed char)(vw3 >> 16), acc[14]);
        acc[15] = fmaf(f, (float)(signed char)(vw3 >> 24), acc[15]);
    }

    // combine the 8 edge-slots: lanes with equal i (xor masks 8,16,32)
    #pragma unroll
    for (int mth = 8; mth <= 32; mth <<= 1) {
        z += __shfl_xor(z, mth, 64);
        #pragma unroll
        for (int t = 0; t < 16; ++t)
            acc[t] += __shfl_xor(acc[t], mth, 64);
    }

    // write: lanes g==0 (one per head) write dims 16i..16i+15
    if (g == 0) {
        const float inv = (nE > 0 && z > 0.f) ? 1.f / z : 0.f;
        const size_t base = (size_t)node * 128 + 16 * i;
        #pragma unroll
        for (int t = 0; t < 4; ++t) {
            ushort4 rb = *reinterpret_cast<const ushort4*>(resb + base + 4 * t);
            float4 o;
            o.x = fmaf(acc[4 * t + 0], inv, bf2f(rb.x));
            o.y = fmaf(acc[4 * t + 1], inv, bf2f(rb.y));
            o.z = fmaf(acc[4 * t + 2], inv, bf2f(rb.z));
            o.w = fmaf(acc[4 * t + 3], inv, bf2f(rb.w));
            *reinterpret_cast<float4*>(rst + base + 4 * t) = o;
        }
    }
}

extern "C" void kernel_launch(void* const* d_in, const int* in_sizes, int n_in,
                              void* d_out, int out_size, void* d_ws, size_t ws_size,
                              hipStream_t stream) {
    const float* h    = (const float*)d_in[0];
    const int*   src  = (const int*)d_in[2];
    const int*   dst  = (const int*)d_in[3];
    const float* Wq   = (const float*)d_in[4];
    const float* Wk   = (const float*)d_in[5];
    const float* Wv   = (const float*)d_in[6];
    const float* Wres = (const float*)d_in[8];
    float* rst = (float*)d_out;

    const int N = in_sizes[0] / 128;   // 50000
    const int E = in_sizes[2];         // 800000

    unsigned short* qb    = (unsigned short*)d_ws;          // N*128 bf16
    unsigned short* resb  = qb + (size_t)N * 128;           // N*128 bf16
    unsigned char*  kvb   = (unsigned char*)(resb + (size_t)N * 128); // N*256 u8
    unsigned short* kvscl = (unsigned short*)(kvb + (size_t)N * 256); // 2N bf16
    unsigned short* wpk   = kvscl + 2 * N;                  // 65536 bf16
    int* cnt       = (int*)(wpk + 4 * 16384);
    int* row_start = cnt + N;          // N+1
    int* cursor    = row_start + (N + 1);
    int* csr_src   = cursor + N;       // E + 64 (padded)
    int* bsum      = csr_src + E + 64;

    const int n4 = N / 4;              // 12500
    const int NB = (N + 1023) / 1024;  // 49 <= 64
    const int PB = (N + 127) / 128;    // proj blocks

    zero_wconv_kernel<<<(8192 + n4 + 255) / 256, 256, 0, stream>>>(
        Wq, Wk, Wv, Wres, wpk, cnt, csr_src + E, n4);
    proj_count_kernel<<<PB + CB, 256, 0, stream>>>(
        h, wpk, qb, kvb, kvscl, resb, dst, cnt, N, E, PB);
    blocksum_kernel<<<NB, 256, 0, stream>>>(cnt, bsum, N);
    scanfinal_kernel<<<NB, 256, 0, stream>>>(cnt, bsum, row_start, cursor,
                                             N, E, NB);
    scatter_kernel<<<(E + 255) / 256, 256, 0, stream>>>(src, dst, cursor,
                                                        csr_src, E);
    head_agg_kernel<<<(N + 3) / 4, 256, 0, stream>>>(
        qb, kvb, (const unsigned int*)kvscl, resb, row_start, csr_src,
        rst, N);
}